// Round 3
// baseline (302.697 us; speedup 1.0000x reference)
//
#include <hip/hip_runtime.h>
#include <hip/hip_bf16.h>

// Attention: out = softmax_causal((xWq+bq)(xWk+bk)^T / sqrt(D)) (xWv+bv) Wo + bo
// B=4, S=2048, D=1024.  All GEMMs in bf16 MFMA (16x16x32), fp32 accumulate.
// R3: BM=128 everywhere + T3-minimum double-buffered 2-phase pipeline
//     (STAGE next K-tile before computing current; one vmcnt(0)+barrier per
//     tile).  Softmax loads/stores vectorized to bf16x8 (16B/lane).

typedef __bf16 bf16x8 __attribute__((ext_vector_type(8)));
typedef __bf16 bf16x4 __attribute__((ext_vector_type(4)));
typedef float  f32x4  __attribute__((ext_vector_type(4)));

#define BDIM 1024
#define SDIM 2048
#define BATCH 4

__device__ __forceinline__ void gload_lds16(const void* g, void* l) {
    __builtin_amdgcn_global_load_lds(
        (const __attribute__((address_space(1))) void*)g,
        (__attribute__((address_space(3))) void*)l, 16, 0, 0);
}

// ---------------- fp32 -> bf16 elementwise ----------------
__global__ __launch_bounds__(256) void cvt_f32_bf16(const float* __restrict__ in,
                                                    __bf16* __restrict__ out, long n) {
    long i = ((long)blockIdx.x * 256 + threadIdx.x) * 4;
    if (i + 3 < n) {
        float4 v = *(const float4*)(in + i);
        bf16x4 o;
        o[0] = (__bf16)v.x; o[1] = (__bf16)v.y; o[2] = (__bf16)v.z; o[3] = (__bf16)v.w;
        *(bf16x4*)(out + i) = o;
    }
}

// ---------------- bias concat [bq|bk|bv] -> bcat[3072] ----------------
__global__ __launch_bounds__(256) void concat3(const float* __restrict__ a,
                                               const float* __restrict__ b,
                                               const float* __restrict__ c,
                                               float* __restrict__ o) {
    int i = blockIdx.x * 256 + threadIdx.x;
    if (i < 3072)
        o[i] = (i < 1024) ? a[i] : ((i < 2048) ? b[i - 1024] : c[i - 2048]);
}

// ---------------- transpose (fp32 or bf16 in) -> bf16 out ----------------
template <typename Tin>
__global__ __launch_bounds__(256) void transpose_to_bf16(const Tin* __restrict__ in,
                                                         __bf16* __restrict__ out,
                                                         int ldIn, int ldOut,
                                                         long sIn, long sOut) {
    __shared__ float tile[32][33];
    const long b = blockIdx.z;
    in += b * sIn; out += b * sOut;
    const int r0 = blockIdx.y * 32, c0 = blockIdx.x * 32;
    const int tx = threadIdx.x, ty = threadIdx.y;  // block (32,8)
    #pragma unroll
    for (int j = ty; j < 32; j += 8)
        tile[j][tx] = (float)in[(long)(r0 + j) * ldIn + (c0 + tx)];
    __syncthreads();
    #pragma unroll
    for (int j = ty; j < 32; j += 8)
        out[(long)(c0 + j) * ldOut + (r0 + tx)] = (__bf16)tile[tx][j];
}

// ---------------- BT GEMM: C[M,N] = A[M,K] * B[N,K]^T (+bias) ----------------
// 128x128 tile, BK=64, 4 waves, 16x16x32 MFMA, double-buffered LDS (64 KiB):
//   prologue STAGE(buf0); loop { STAGE(buf^1, t+1); compute(buf); sync; }
// CSKIP: skip tiles entirely above the causal diagonal (bx > by).
// CKB:   bound K-loop to (by+1)*128 (PV: P causally zero past the q tile).
template <typename Tout, bool CSKIP, bool CKB>
__global__ __launch_bounds__(256) void gemm_bt(const __bf16* __restrict__ Ag,
                                               const __bf16* __restrict__ Bg,
                                               Tout* __restrict__ Cg,
                                               const float* __restrict__ bias,
                                               int N, int K, int lda, int ldb, int ldc,
                                               long sA, long sB, long sC) {
    const int bx = blockIdx.x, by = blockIdx.y;
    if (CSKIP && bx > by) return;
    const __bf16* A = Ag + (long)blockIdx.z * sA;
    const __bf16* B = Bg + (long)blockIdx.z * sB;
    Tout* C = Cg + (long)blockIdx.z * sC;

    __shared__ __align__(16) __bf16 As[2][128 * 64];
    __shared__ __align__(16) __bf16 Bs[2][128 * 64];

    const int tid = threadIdx.x;
    const int w = tid >> 6, l = tid & 63;
    const int m0 = by * 128, n0 = bx * 128;
    const int wr = (w >> 1) * 64, wc = (w & 1) * 64;   // wave's 64x64 quadrant
    const int fr = l & 15, fk = (l >> 4) * 8;          // fragment row / k-offset
    const int srow = tid >> 3;                          // staging row [0,32)
    const int skk = (tid & 7) * 8;                      // staging k offset
    const int kEnd = CKB ? min(K, (by + 1) * 128) : K;
    const int nt = kEnd >> 6;                           // K-tiles (kEnd % 64 == 0)

    f32x4 acc[4][4] = {};

    auto stage = [&](int buf, int k0) {
        #pragma unroll
        for (int it = 0; it < 4; ++it) {
            gload_lds16(A + (long)(m0 + it * 32 + srow) * lda + (k0 + skk),
                        &As[buf][it * 2048 + w * 512]);
            gload_lds16(B + (long)(n0 + it * 32 + srow) * ldb + (k0 + skk),
                        &Bs[buf][it * 2048 + w * 512]);
        }
    };
    auto compute = [&](int buf) {
        #pragma unroll
        for (int ks = 0; ks < 2; ++ks) {
            bf16x8 af[4], bfr[4];
            #pragma unroll
            for (int i = 0; i < 4; ++i) {
                af[i]  = *(const bf16x8*)(&As[buf][(wr + i * 16 + fr) * 64 + ks * 32 + fk]);
                bfr[i] = *(const bf16x8*)(&Bs[buf][(wc + i * 16 + fr) * 64 + ks * 32 + fk]);
            }
            #pragma unroll
            for (int i = 0; i < 4; ++i)
                #pragma unroll
                for (int j = 0; j < 4; ++j)
                    acc[i][j] = __builtin_amdgcn_mfma_f32_16x16x32_bf16(af[i], bfr[j],
                                                                        acc[i][j], 0, 0, 0);
        }
    };

    // software pipeline: prefetch next K-tile while computing current
    stage(0, 0);
    __syncthreads();                 // vmcnt(0) drain + barrier
    int cur = 0;
    for (int t = 0; t < nt - 1; ++t) {
        stage(cur ^ 1, (t + 1) * 64);   // issue next-tile loads (other buffer)
        compute(cur);                    // ds_read + 32 MFMA on current
        __syncthreads();                 // drain prefetch + barrier
        cur ^= 1;
    }
    compute(cur);                        // last tile, no prefetch

    // epilogue: C/D layout col = lane&15, row = (lane>>4)*4 + reg  [m89-verified]
    const int rbase = (l >> 4) * 4;
    const int cl = l & 15;
    #pragma unroll
    for (int j = 0; j < 4; ++j) {
        const int col = n0 + wc + j * 16 + cl;
        const float bv = bias ? bias[col] : 0.f;
        #pragma unroll
        for (int i = 0; i < 4; ++i)
            #pragma unroll
            for (int r = 0; r < 4; ++r) {
                const int rowi = m0 + wr + i * 16 + rbase + r;
                C[(long)rowi * ldc + col] = (Tout)(acc[i][j][r] + bv);
            }
    }
}

// ---------------- causal softmax row kernel (vectorized 16B/lane) ------------
// P[q][k] = softmax_k(scale * scores[q][k], k <= q), zeros for k > q.
__global__ __launch_bounds__(256) void softmax_causal(const __bf16* __restrict__ scores,
                                                      __bf16* __restrict__ P, float scale) {
    const int q = blockIdx.x;
    const long b = blockIdx.y;
    const __bf16* srow = scores + (b * SDIM + q) * (long)SDIM;
    __bf16* prow = P + (b * SDIM + q) * (long)SDIM;
    const int n = q + 1;
    const int tid = threadIdx.x;
    const int k0 = tid * 8;                    // 256 threads x 8 = 2048 row elems
    __shared__ float red[8];

    const bf16x8 v = *(const bf16x8*)(srow + k0);
    float vals[8];
    float mx = -1e30f;
    #pragma unroll
    for (int i = 0; i < 8; ++i) {
        const float s = (k0 + i < n) ? (float)v[i] * scale : -1e30f;
        vals[i] = s;
        mx = fmaxf(mx, s);
    }
    #pragma unroll
    for (int o = 32; o > 0; o >>= 1) mx = fmaxf(mx, __shfl_xor(mx, o));
    if ((tid & 63) == 0) red[tid >> 6] = mx;
    __syncthreads();
    mx = fmaxf(fmaxf(red[0], red[1]), fmaxf(red[2], red[3]));

    float p[8];
    float sum = 0.f;
    #pragma unroll
    for (int i = 0; i < 8; ++i) {
        p[i] = __expf(vals[i] - mx);           // masked lanes: exp(-huge) -> 0
        sum += p[i];
    }
    #pragma unroll
    for (int o = 32; o > 0; o >>= 1) sum += __shfl_xor(sum, o);
    if ((tid & 63) == 0) red[4 + (tid >> 6)] = sum;
    __syncthreads();
    sum = red[4] + red[5] + red[6] + red[7];

    const float inv = 1.f / sum;
    bf16x8 o;
    #pragma unroll
    for (int i = 0; i < 8; ++i)
        o[i] = (__bf16)((k0 + i < n) ? p[i] * inv : 0.f);
    *(bf16x8*)(prow + k0) = o;
}

extern "C" void kernel_launch(void* const* d_in, const int* in_sizes, int n_in,
                              void* d_out, int out_size, void* d_ws, size_t ws_size,
                              hipStream_t stream) {
    const float* x  = (const float*)d_in[0];
    // d_in[1] = mask (tril ones) -- causality enforced by index, unused.
    const float* Wq = (const float*)d_in[2];
    const float* bq = (const float*)d_in[3];
    const float* Wk = (const float*)d_in[4];
    const float* bk = (const float*)d_in[5];
    const float* Wv = (const float*)d_in[6];
    const float* bv = (const float*)d_in[7];
    const float* Wo = (const float*)d_in[8];
    const float* bo = (const float*)d_in[9];
    float* out = (float*)d_out;

    char* ws = (char*)d_ws;
    const long MT = (long)BATCH * SDIM;           // 8192 total rows
    const long XE = MT * BDIM;                    // 8,388,608 elements
    __bf16* xb   = (__bf16*)(ws);                 // 16 MiB   [ctx aliases later]
    __bf16* Wcat = (__bf16*)(ws + 16777216);      // 6 MiB   [Wq|Wk|Wv]^T (3072x1024)
    __bf16* Wot  = (__bf16*)(ws + 23068672);      // 2 MiB
    float*  bcat = (float*)(ws + 25165824);       // 12 KiB
    __bf16* QKVb = (__bf16*)(ws + 25178112);      // 48 MiB  (8192 x 3072)
    __bf16* Vtb  = (__bf16*)(ws + 75509760);      // 16 MiB  (B x [1024][2048])
    __bf16* Sc   = (__bf16*)(ws + 92286976);      // 32 MiB  scores
    __bf16* Pb   = (__bf16*)(ws + 25178112);      // alias QKVb (dead after QK^T/Vt)
    __bf16* ctxb = (__bf16*)(ws);                 // alias xb  (dead after QKV proj)

    const long SD  = (long)SDIM * BDIM;           // 2,097,152
    const long SS  = (long)SDIM * SDIM;           // 4,194,304
    const long SQ3 = (long)SDIM * 3 * BDIM;       // 6,291,456 (batch stride in QKVb)

    // 1) x -> bf16
    cvt_f32_bf16<<<dim3((unsigned)(XE / 4 / 256)), 256, 0, stream>>>(x, xb, XE);
    // 2) weights -> transposed bf16; QKV weights packed into Wcat rows [0|1024|2048)
    transpose_to_bf16<float><<<dim3(32, 32, 1), dim3(32, 8), 0, stream>>>(Wq, Wcat,             BDIM, BDIM, 0, 0);
    transpose_to_bf16<float><<<dim3(32, 32, 1), dim3(32, 8), 0, stream>>>(Wk, Wcat + 1024*1024, BDIM, BDIM, 0, 0);
    transpose_to_bf16<float><<<dim3(32, 32, 1), dim3(32, 8), 0, stream>>>(Wv, Wcat + 2048*1024, BDIM, BDIM, 0, 0);
    transpose_to_bf16<float><<<dim3(32, 32, 1), dim3(32, 8), 0, stream>>>(Wo, Wot,              BDIM, BDIM, 0, 0);
    concat3<<<dim3(12), 256, 0, stream>>>(bq, bk, bv, bcat);
    // 3) merged projection: QKV[8192][3072] = x @ Wcat^T + bcat
    gemm_bt<__bf16, false, false><<<dim3(24, 64, 1), 256, 0, stream>>>(
        xb, Wcat, QKVb, bcat, 3072, BDIM, BDIM, BDIM, 3072, 0, 0, 0);
    // 4) V^T per batch: [S,1024] (stride 3072 inside QKV) -> [1024][S]
    transpose_to_bf16<__bf16><<<dim3(32, 64, BATCH), dim3(32, 8), 0, stream>>>(
        QKVb + 2048, Vtb, 3072, SDIM, SQ3, SD);
    // 5) scores = Q @ K^T per batch (causal tile skip), raw logits in bf16
    gemm_bt<__bf16, true, false><<<dim3(16, 16, BATCH), 256, 0, stream>>>(
        QKVb, QKVb + 1024, Sc, nullptr, SDIM, BDIM, 3072, 3072, SDIM, SQ3, SQ3, SS);
    // 6) causal softmax (scale = 1/32)
    softmax_causal<<<dim3(SDIM, BATCH), 256, 0, stream>>>(Sc, Pb, 0.03125f);
    // 7) ctx = P @ V   (B operand = V^T, K-loop causally bounded)
    gemm_bt<__bf16, false, true><<<dim3(8, 16, BATCH), 256, 0, stream>>>(
        Pb, Vtb, ctxb, nullptr, BDIM, SDIM, SDIM, SDIM, BDIM, SS, SD, SD);
    // 8) out = ctx @ Wo + bo (fp32 output)
    gemm_bt<float, false, false><<<dim3(8, 64, 1), 256, 0, stream>>>(
        ctxb, Wot, out, bo, BDIM, BDIM, BDIM, BDIM, BDIM, 0, 0, 0);
}

// Round 4
// 260.912 us; speedup vs baseline: 1.1601x; 1.1601x over previous
//
#include <hip/hip_runtime.h>
#include <hip/hip_bf16.h>

// Attention: out = softmax_causal((xWq+bq)(xWk+bk)^T / sqrt(D)) (xWv+bv) Wo + bo
// B=4, S=2048, D=1024.  All GEMMs bf16 MFMA 16x16x32, fp32 accumulate.
// R4: 256x256-tile 8-wave GEMM, BK=32, double-buffered LDS (64 KiB) with
//     COUNTED vmcnt (loads in flight across barriers, T3+T4), st_16x32 LDS
//     swizzle via pre-swizzled global source (T2, rule #21), setprio around
//     MFMA clusters (T5).  Raw s_barrier + memory-clobber fences.

typedef __bf16 bf16x8 __attribute__((ext_vector_type(8)));
typedef __bf16 bf16x4 __attribute__((ext_vector_type(4)));
typedef float  f32x4  __attribute__((ext_vector_type(4)));

#define BDIM 1024
#define SDIM 2048
#define BATCH 4

__device__ __forceinline__ void gload_lds16(const void* g, void* l) {
    __builtin_amdgcn_global_load_lds(
        (const __attribute__((address_space(1))) void*)g,
        (__attribute__((address_space(3))) void*)l, 16, 0, 0);
}

// ---------------- fp32 -> bf16 elementwise ----------------
__global__ __launch_bounds__(256) void cvt_f32_bf16(const float* __restrict__ in,
                                                    __bf16* __restrict__ out, long n) {
    long i = ((long)blockIdx.x * 256 + threadIdx.x) * 4;
    if (i + 3 < n) {
        float4 v = *(const float4*)(in + i);
        bf16x4 o;
        o[0] = (__bf16)v.x; o[1] = (__bf16)v.y; o[2] = (__bf16)v.z; o[3] = (__bf16)v.w;
        *(bf16x4*)(out + i) = o;
    }
}

// ---------------- bias concat [bq|bk|bv] -> bcat[3072] ----------------
__global__ __launch_bounds__(256) void concat3(const float* __restrict__ a,
                                               const float* __restrict__ b,
                                               const float* __restrict__ c,
                                               float* __restrict__ o) {
    int i = blockIdx.x * 256 + threadIdx.x;
    if (i < 3072)
        o[i] = (i < 1024) ? a[i] : ((i < 2048) ? b[i - 1024] : c[i - 2048]);
}

// ---------------- transpose (fp32 or bf16 in) -> bf16 out ----------------
template <typename Tin>
__global__ __launch_bounds__(256) void transpose_to_bf16(const Tin* __restrict__ in,
                                                         __bf16* __restrict__ out,
                                                         int ldIn, int ldOut,
                                                         long sIn, long sOut) {
    __shared__ float tile[32][33];
    const long b = blockIdx.z;
    in += b * sIn; out += b * sOut;
    const int r0 = blockIdx.y * 32, c0 = blockIdx.x * 32;
    const int tx = threadIdx.x, ty = threadIdx.y;  // block (32,8)
    #pragma unroll
    for (int j = ty; j < 32; j += 8)
        tile[j][tx] = (float)in[(long)(r0 + j) * ldIn + (c0 + tx)];
    __syncthreads();
    #pragma unroll
    for (int j = ty; j < 32; j += 8)
        out[(long)(c0 + j) * ldOut + (r0 + tx)] = (__bf16)tile[tx][j];
}

// ---------------- 256x256 BT GEMM: C = A[M,K] * B[N,K]^T (+bias) -------------
// 8 waves (2M x 4N), per-wave 128x64 output = acc[8][4].  BK=32, dbuf LDS.
// LDS layout per tile: subtiled [r>>4][r&15][c] (1 KiB per 16x32 subtile) with
// st_16x32 XOR swizzle (flip byte-bit5 when r&8) folded into per-lane const cA.
// Staging: global_load_lds 16B/lane, linear LDS dest, INVERSE-swizzled global
// source (rule #21).  Pipeline: stage t+2 after reads of buf(t) done; counted
// s_waitcnt vmcnt(4) guarantees tile t+1 landed; never vmcnt(0) mid-loop.
template <typename Tout, bool CSKIP, bool CKB>
__global__ __launch_bounds__(512, 2) void gemm256(const __bf16* __restrict__ Ag,
                                                  const __bf16* __restrict__ Bg,
                                                  Tout* __restrict__ Cg,
                                                  const float* __restrict__ bias,
                                                  int K, int lda, int ldb, int ldc,
                                                  long sA, long sB, long sC) {
    const int bx = blockIdx.x, by = blockIdx.y;
    if (CSKIP && bx > by) return;  // tile fully above causal diagonal
    const __bf16* A = Ag + (long)blockIdx.z * sA;
    const __bf16* B = Bg + (long)blockIdx.z * sB;
    Tout* C = Cg + (long)blockIdx.z * sC;

    __shared__ __align__(16) char smem[65536];  // 2 bufs x (A 16K + B 16K)

    const int tid = threadIdx.x;                // 0..511
    const int wid = tid >> 6, l = tid & 63;
    const int wm = wid >> 2, wn = wid & 3;      // wave grid 2(M) x 4(N)
    const int m0 = by * 256, n0 = bx * 256;

    // staging source element offsets: invert (subtile layout + XOR swizzle)
    // for the linear LDS byte this lane's load lands at.
    int srcA[2], srcB[2];
    #pragma unroll
    for (int i = 0; i < 2; ++i) {
        const int beta = i * 8192 + tid * 16;           // linear LDS byte
        const int s = beta & 1023, rg = beta >> 10;
        const int sp = s ^ (((s >> 9) & 1) << 5);       // unswizzle (involution)
        const int r = rg * 16 + (sp >> 6);              // logical row 0..255
        const int c = (sp & 63) >> 1;                   // logical col 0..31
        srcA[i] = (m0 + r) * lda + c;
        srcB[i] = (n0 + r) * ldb + c;
    }
    const int ldsOff = wid * 1024;  // wave-uniform dest base (HW adds lane*16)
    // swizzled per-lane read offset within a 16-row subtile:
    const int cA = (l & 15) * 64 + (((l >> 4) * 16) ^ ((l & 8) << 2));

    f32x4 acc[8][4] = {};
    const int kEnd = CKB ? min(K, (by + 1) * 256) : K;
    const int nt = kEnd >> 5;  // K-tiles of 32 (kEnd % 32 == 0 by construction)

    auto stage = [&](int buf, int k0) {
        char* Ab = smem + buf * 32768;
        char* Bb = Ab + 16384;
        #pragma unroll
        for (int i = 0; i < 2; ++i) {
            gload_lds16(A + srcA[i] + k0, Ab + i * 8192 + ldsOff);
            gload_lds16(B + srcB[i] + k0, Bb + i * 8192 + ldsOff);
        }
    };

    // prologue: two tiles in flight; wait only for the first (vmcnt 4 = tile 1)
    stage(0, 0);
    stage(1, 32);
    asm volatile("s_waitcnt vmcnt(4)" ::: "memory");
    __builtin_amdgcn_s_barrier();
    asm volatile("" ::: "memory");

    for (int t = 0; t < nt; ++t) {
        const int cur = t & 1;
        const char* Ab = smem + cur * 32768;
        const char* Bb = Ab + 16384;
        bf16x8 bfr[4], afr[4];
        #pragma unroll
        for (int n = 0; n < 4; ++n)
            bfr[n] = *(const bf16x8*)(Bb + (wn * 4 + n) * 1024 + cA);
        #pragma unroll
        for (int m = 0; m < 4; ++m)
            afr[m] = *(const bf16x8*)(Ab + (wm * 8 + m) * 1024 + cA);
        __builtin_amdgcn_s_setprio(1);
        #pragma unroll
        for (int m = 0; m < 4; ++m)
            #pragma unroll
            for (int n = 0; n < 4; ++n)
                acc[m][n] = __builtin_amdgcn_mfma_f32_16x16x32_bf16(afr[m], bfr[n],
                                                                    acc[m][n], 0, 0, 0);
        __builtin_amdgcn_s_setprio(0);
        #pragma unroll
        for (int m = 0; m < 4; ++m)
            afr[m] = *(const bf16x8*)(Ab + (wm * 8 + 4 + m) * 1024 + cA);
        __builtin_amdgcn_s_setprio(1);
        #pragma unroll
        for (int m = 0; m < 4; ++m)
            #pragma unroll
            for (int n = 0; n < 4; ++n)
                acc[4 + m][n] = __builtin_amdgcn_mfma_f32_16x16x32_bf16(afr[m], bfr[n],
                                                                        acc[4 + m][n], 0, 0, 0);
        __builtin_amdgcn_s_setprio(0);

        // all waves done reading buf `cur` (own ds_reads completed before the
        // last MFMA via compiler lgkmcnt; fences stop compiler reordering)
        asm volatile("" ::: "memory");
        __builtin_amdgcn_s_barrier();
        asm volatile("" ::: "memory");
        if (t + 2 < nt) {
            stage(cur, (t + 2) * 32);                       // refill freed buf
            asm volatile("s_waitcnt vmcnt(4)" ::: "memory"); // tile t+1 landed
            __builtin_amdgcn_s_barrier();
            asm volatile("" ::: "memory");
        } else if (t + 1 < nt) {
            asm volatile("s_waitcnt vmcnt(0)" ::: "memory"); // drain last tile
            __builtin_amdgcn_s_barrier();
            asm volatile("" ::: "memory");
        }
    }

    // epilogue: C/D layout col = lane&15, row = (lane>>4)*4 + reg [m89-verified]
    const int rb = (l >> 4) * 4, cl = l & 15;
    #pragma unroll
    for (int n = 0; n < 4; ++n) {
        const int col = n0 + wn * 64 + n * 16 + cl;
        const float bv = bias ? bias[col] : 0.f;
        #pragma unroll
        for (int m = 0; m < 8; ++m) {
            const int row = m0 + wm * 128 + m * 16 + rb;
            #pragma unroll
            for (int r = 0; r < 4; ++r)
                C[(long)(row + r) * ldc + col] = (Tout)(acc[m][n][r] + bv);
        }
    }
}

// ---------------- causal softmax row kernel (16B/lane) ----------------
__global__ __launch_bounds__(256) void softmax_causal(const __bf16* __restrict__ scores,
                                                      __bf16* __restrict__ P, float scale) {
    const int q = blockIdx.x;
    const long b = blockIdx.y;
    const __bf16* srow = scores + (b * SDIM + q) * (long)SDIM;
    __bf16* prow = P + (b * SDIM + q) * (long)SDIM;
    const int n = q + 1;
    const int tid = threadIdx.x;
    const int k0 = tid * 8;
    __shared__ float red[8];

    const bf16x8 v = *(const bf16x8*)(srow + k0);
    float vals[8];
    float mx = -1e30f;
    #pragma unroll
    for (int i = 0; i < 8; ++i) {
        const float s = (k0 + i < n) ? (float)v[i] * scale : -1e30f;
        vals[i] = s;
        mx = fmaxf(mx, s);
    }
    #pragma unroll
    for (int o = 32; o > 0; o >>= 1) mx = fmaxf(mx, __shfl_xor(mx, o));
    if ((tid & 63) == 0) red[tid >> 6] = mx;
    __syncthreads();
    mx = fmaxf(fmaxf(red[0], red[1]), fmaxf(red[2], red[3]));

    float p[8];
    float sum = 0.f;
    #pragma unroll
    for (int i = 0; i < 8; ++i) {
        p[i] = __expf(vals[i] - mx);
        sum += p[i];
    }
    #pragma unroll
    for (int o = 32; o > 0; o >>= 1) sum += __shfl_xor(sum, o);
    if ((tid & 63) == 0) red[4 + (tid >> 6)] = sum;
    __syncthreads();
    sum = red[4] + red[5] + red[6] + red[7];

    const float inv = 1.f / sum;
    bf16x8 o;
    #pragma unroll
    for (int i = 0; i < 8; ++i)
        o[i] = (__bf16)((k0 + i < n) ? p[i] * inv : 0.f);
    *(bf16x8*)(prow + k0) = o;
}

extern "C" void kernel_launch(void* const* d_in, const int* in_sizes, int n_in,
                              void* d_out, int out_size, void* d_ws, size_t ws_size,
                              hipStream_t stream) {
    const float* x  = (const float*)d_in[0];
    // d_in[1] = mask (tril ones) -- causality enforced by index, unused.
    const float* Wq = (const float*)d_in[2];
    const float* bq = (const float*)d_in[3];
    const float* Wk = (const float*)d_in[4];
    const float* bk = (const float*)d_in[5];
    const float* Wv = (const float*)d_in[6];
    const float* bv = (const float*)d_in[7];
    const float* Wo = (const float*)d_in[8];
    const float* bo = (const float*)d_in[9];
    float* out = (float*)d_out;

    char* ws = (char*)d_ws;
    const long MT = (long)BATCH * SDIM;           // 8192 rows
    const long XE = MT * BDIM;
    __bf16* xb   = (__bf16*)(ws);                 // 16 MiB [ctx aliases later]
    __bf16* Wcat = (__bf16*)(ws + 16777216);      // 6 MiB  [Wq|Wk|Wv]^T
    __bf16* Wot  = (__bf16*)(ws + 23068672);      // 2 MiB
    float*  bcat = (float*)(ws + 25165824);       // 12 KiB
    __bf16* QKVb = (__bf16*)(ws + 25178112);      // 48 MiB (8192 x 3072)
    __bf16* Vtb  = (__bf16*)(ws + 75509760);      // 16 MiB (B x [1024][2048])
    __bf16* Sc   = (__bf16*)(ws + 92286976);      // 32 MiB scores
    __bf16* Pb   = (__bf16*)(ws + 25178112);      // alias QKVb
    __bf16* ctxb = (__bf16*)(ws);                 // alias xb

    const long SD  = (long)SDIM * BDIM;
    const long SS  = (long)SDIM * SDIM;
    const long SQ3 = (long)SDIM * 3 * BDIM;

    cvt_f32_bf16<<<dim3((unsigned)(XE / 4 / 256)), 256, 0, stream>>>(x, xb, XE);
    transpose_to_bf16<float><<<dim3(32, 32, 1), dim3(32, 8), 0, stream>>>(Wq, Wcat,             BDIM, BDIM, 0, 0);
    transpose_to_bf16<float><<<dim3(32, 32, 1), dim3(32, 8), 0, stream>>>(Wk, Wcat + 1024*1024, BDIM, BDIM, 0, 0);
    transpose_to_bf16<float><<<dim3(32, 32, 1), dim3(32, 8), 0, stream>>>(Wv, Wcat + 2048*1024, BDIM, BDIM, 0, 0);
    transpose_to_bf16<float><<<dim3(32, 32, 1), dim3(32, 8), 0, stream>>>(Wo, Wot,              BDIM, BDIM, 0, 0);
    concat3<<<dim3(12), 256, 0, stream>>>(bq, bk, bv, bcat);
    // QKV[8192][3072] = x @ Wcat^T + bcat          grid 12x32 = 384 blocks
    gemm256<__bf16, false, false><<<dim3(12, 32, 1), 512, 0, stream>>>(
        xb, Wcat, QKVb, bcat, BDIM, BDIM, BDIM, 3072, 0, 0, 0);
    // V^T per batch: [S,1024] (stride 3072) -> [1024][S]
    transpose_to_bf16<__bf16><<<dim3(32, 64, BATCH), dim3(32, 8), 0, stream>>>(
        QKVb + 2048, Vtb, 3072, SDIM, SQ3, SD);
    // scores = Q @ K^T per batch, causal tile skip    grid 8x8x4 (36x4 live)
    gemm256<__bf16, true, false><<<dim3(8, 8, BATCH), 512, 0, stream>>>(
        QKVb, QKVb + 1024, Sc, nullptr, BDIM, 3072, 3072, SDIM, SQ3, SQ3, SS);
    softmax_causal<<<dim3(SDIM, BATCH), 256, 0, stream>>>(Sc, Pb, 0.03125f);
    // ctx = P @ V (B = V^T, K causally bounded)       grid 4x8x4
    gemm256<__bf16, false, true><<<dim3(4, 8, BATCH), 512, 0, stream>>>(
        Pb, Vtb, ctxb, nullptr, SDIM, SDIM, SDIM, BDIM, SS, SD, SD);
    // out = ctx @ Wo + bo                             grid 4x32
    gemm256<float, false, false><<<dim3(4, 32, 1), 512, 0, stream>>>(
        ctxb, Wot, out, bo, BDIM, BDIM, BDIM, BDIM, 0, 0, 0);
}